// Round 2
// baseline (308.500 us; speedup 1.0000x reference)
//
#include <hip/hip_runtime.h>
#include <hip/hip_bf16.h>

#define D 64

__device__ __forceinline__ float lane_bcast(float v, int l) {
    return __int_as_float(__builtin_amdgcn_readlane(__float_as_int(v), l));
}

// ---- CSR build ------------------------------------------------------------
// NOTE: harness delivers integer inputs as int32 (edge_index -> const int*).

__global__ void count_k(const int* __restrict__ dst, int* __restrict__ cnt, int E) {
    int e = blockIdx.x * blockDim.x + threadIdx.x;
    if (e < E) atomicAdd(&cnt[dst[e]], 1);
}

__global__ void scanA_k(const int* __restrict__ cnt, int* __restrict__ rowptr,
                        int* __restrict__ bsum, int N) {
    __shared__ int tmp[256];
    int gid = blockIdx.x * 256 + threadIdx.x;
    int v = (gid < N) ? cnt[gid] : 0;
    tmp[threadIdx.x] = v;
    __syncthreads();
    for (int off = 1; off < 256; off <<= 1) {
        int t = (threadIdx.x >= off) ? tmp[threadIdx.x - off] : 0;
        __syncthreads();
        tmp[threadIdx.x] += t;
        __syncthreads();
    }
    if (gid < N) rowptr[gid] = tmp[threadIdx.x] - v;   // exclusive within block
    if (threadIdx.x == 255) bsum[blockIdx.x] = tmp[255];
}

__global__ void scanB_k(int* __restrict__ bsum, int nb) {  // nb <= 256
    __shared__ int tmp[256];
    int v = (threadIdx.x < nb) ? bsum[threadIdx.x] : 0;
    tmp[threadIdx.x] = v;
    __syncthreads();
    for (int off = 1; off < 256; off <<= 1) {
        int t = (threadIdx.x >= off) ? tmp[threadIdx.x - off] : 0;
        __syncthreads();
        tmp[threadIdx.x] += t;
        __syncthreads();
    }
    if (threadIdx.x < nb) bsum[threadIdx.x] = tmp[threadIdx.x] - v;  // exclusive
}

__global__ void scanC_k(int* __restrict__ rowptr, int* __restrict__ cursor,
                        const int* __restrict__ bsum, int N, int E) {
    int gid = blockIdx.x * 256 + threadIdx.x;
    if (gid < N) {
        int v = rowptr[gid] + bsum[blockIdx.x];
        rowptr[gid] = v;
        cursor[gid] = v;
    }
    if (blockIdx.x == 0 && threadIdx.x == 0) rowptr[N] = E;
}

__global__ void fill_k(const int* __restrict__ src, const int* __restrict__ dst,
                       int* __restrict__ cursor, int* __restrict__ col, int E) {
    int e = blockIdx.x * blockDim.x + threadIdx.x;
    if (e < E) {
        int d = dst[e];
        int pos = atomicAdd(&cursor[d], 1);
        col[pos] = src[e];
    }
}

// ---- fused SAGE layer: mean-gather + dual GEMM + bias (+tanh) --------------
// One wave per node. lane = feature dim. Weights transposed in LDS so the
// per-k read sWl[k*64+lane] is lane-contiguous (2 lanes/bank = free).

template <bool TANH>
__global__ __launch_bounds__(256) void sage_k(
    const float* __restrict__ xin, const int* __restrict__ rowptr,
    const int* __restrict__ col,
    const float* __restrict__ Wl, const float* __restrict__ Wr,
    const float* __restrict__ bias,
    float* __restrict__ out, int N)
{
    __shared__ float sWl[D * D];
    __shared__ float sWr[D * D];
    for (int i = threadIdx.x; i < D * D; i += blockDim.x) {
        int r = i >> 6, c = i & 63;
        sWl[c * D + r] = Wl[i];   // store W^T: sW[k][i] = W[i][k]
        sWr[c * D + r] = Wr[i];
    }
    __syncthreads();

    const int lane = threadIdx.x & 63;
    const int wid  = threadIdx.x >> 6;
    const int wpb  = blockDim.x >> 6;
    const float bv = bias[lane];

    for (int n = blockIdx.x * wpb + wid; n < N; n += gridDim.x * wpb) {
        const int beg = rowptr[n], end = rowptr[n + 1];
        float a0 = 0.f, a1 = 0.f, a2 = 0.f, a3 = 0.f;
        int j = beg;
        for (; j + 4 <= end; j += 4) {          // 4 outstanding gathers
            int c0 = col[j], c1 = col[j + 1], c2 = col[j + 2], c3 = col[j + 3];
            a0 += xin[(size_t)c0 * D + lane];
            a1 += xin[(size_t)c1 * D + lane];
            a2 += xin[(size_t)c2 * D + lane];
            a3 += xin[(size_t)c3 * D + lane];
        }
        for (; j < end; ++j) a0 += xin[(size_t)col[j] * D + lane];

        float agg = (a0 + a1) + (a2 + a3);
        agg *= 1.0f / fmaxf((float)(end - beg), 1.0f);   // mean with deg>=1 guard
        const float xv = xin[(size_t)n * D + lane];

        float o0 = bv, o1 = 0.f;                // two chains: half dep latency
        #pragma unroll
        for (int k = 0; k < D; ++k) {
            float ak = lane_bcast(agg, k);      // v_readlane -> SGPR broadcast
            float xk = lane_bcast(xv, k);
            o0 = fmaf(sWl[k * D + lane], ak, o0);
            o1 = fmaf(sWr[k * D + lane], xk, o1);
        }
        float o = o0 + o1;
        if (TANH) o = tanhf(o);
        out[(size_t)n * D + lane] = o;
    }
}

// ---- launcher ---------------------------------------------------------------

extern "C" void kernel_launch(void* const* d_in, const int* in_sizes, int n_in,
                              void* d_out, int out_size, void* d_ws, size_t ws_size,
                              hipStream_t stream) {
    const float* x    = (const float*)d_in[0];
    const int*   ei   = (const int*)d_in[1];     // int64 in ref -> int32 here
    const float* Wl1  = (const float*)d_in[2];
    const float* bl1  = (const float*)d_in[3];
    const float* Wr1  = (const float*)d_in[4];
    const float* Wl2  = (const float*)d_in[5];
    const float* bl2  = (const float*)d_in[6];
    const float* Wr2  = (const float*)d_in[7];

    const int N = in_sizes[0] / D;
    const int E = in_sizes[1] / 2;
    const int* srcI = ei;        // edge_index[0]
    const int* dstI = ei + E;    // edge_index[1]

    auto al = [](size_t v) { return (v + 255) & ~(size_t)255; };
    char* w = (char*)d_ws;
    size_t off = 0;
    int*   cnt    = (int*)(w + off);  off += al((size_t)N * 4);
    int*   rowptr = (int*)(w + off);  off += al((size_t)(N + 1) * 4);
    int*   cursor = (int*)(w + off);  off += al((size_t)N * 4);
    int*   bsum   = (int*)(w + off);  off += al(1024);
    int*   colA   = (int*)(w + off);  off += al((size_t)E * 4);
    float* h      = (float*)(w + off);  // [N, D] fp32, layer-1 output

    const int NB = (N + 255) / 256;   // 196 blocks; scanB handles NB<=256

    hipMemsetAsync(cnt, 0, (size_t)N * 4, stream);
    count_k<<<(E + 255) / 256, 256, 0, stream>>>(dstI, cnt, E);
    scanA_k<<<NB, 256, 0, stream>>>(cnt, rowptr, bsum, N);
    scanB_k<<<1, 256, 0, stream>>>(bsum, NB);
    scanC_k<<<NB, 256, 0, stream>>>(rowptr, cursor, bsum, N, E);
    fill_k<<<(E + 255) / 256, 256, 0, stream>>>(srcI, dstI, cursor, colA, E);

    float* out = (float*)d_out;
    // 32 KiB LDS/block -> 5 blocks/CU; 1280 blocks covers 256 CUs, grid-stride.
    sage_k<true ><<<1280, 256, 0, stream>>>(x, rowptr, colA, Wl1, Wr1, bl1, h,   N);
    sage_k<false><<<1280, 256, 0, stream>>>(h, rowptr, colA, Wl2, Wr2, bl2, out, N);
}